// Round 1
// baseline (417.014 us; speedup 1.0000x reference)
//
#include <hip/hip_runtime.h>

constexpr int D = 1024;
constexpr int CH = 24, CW = 24, OH = 96, OW = 96;
constexpr int NTOK = CH * CW;   // 576
constexpr float EPS = 1e-12f;

__device__ inline float wave_reduce_sum(float v) {
#pragma unroll
    for (int off = 32; off > 0; off >>= 1)
        v += __shfl_down(v, off, 64);
    return v;   // lane 0 holds the full sum
}

// One block per compressed token. 4 waves; each wave handles 4 of the 16
// window (original) tokens. Lane L covers dims {j*256 + L*4 .. +3}, j=0..3
// -> perfectly coalesced float4 loads (1 KiB per wave per instruction).
__global__ __launch_bounds__(256) void rf_partial_kernel(
    const float* __restrict__ comp, const float* __restrict__ orig,
    float* __restrict__ partial)
{
    const int blk  = blockIdx.x;          // b*576 + t
    const int b    = blk / NTOK;
    const int t    = blk - b * NTOK;
    const int ch   = t / CW;
    const int cw   = t - ch * CW;
    const int tid  = threadIdx.x;
    const int wave = tid >> 6;
    const int lane = tid & 63;

    const float* cbase = comp + (size_t)blk * D;

    float4 c[4];
    float cc = 0.f;
#pragma unroll
    for (int j = 0; j < 4; ++j) {
        c[j] = *(const float4*)(cbase + j * 256 + lane * 4);
        cc += c[j].x * c[j].x + c[j].y * c[j].y + c[j].z * c[j].z + c[j].w * c[j].w;
    }
    cc = wave_reduce_sum(cc);             // lane 0: ||c||^2

    float wsum = 0.f;                     // accumulated on lane 0 only
#pragma unroll
    for (int k = 0; k < 4; ++k) {
        const int kk = wave * 4 + k;      // window element 0..15
        const int h  = ch * 4 + (kk >> 2);
        const int w  = cw * 4 + (kk & 3);
        const float* obase = orig + ((size_t)b * (OH * OW) + h * OW + w) * D;

        float dco = 0.f, doo = 0.f;
#pragma unroll
        for (int j = 0; j < 4; ++j) {
            float4 o = *(const float4*)(obase + j * 256 + lane * 4);
            dco += c[j].x * o.x + c[j].y * o.y + c[j].z * o.z + c[j].w * o.w;
            doo += o.x * o.x + o.y * o.y + o.z * o.z + o.w * o.w;
        }
        dco = wave_reduce_sum(dco);
        doo = wave_reduce_sum(doo);
        if (lane == 0) {
            float nc = fmaxf(sqrtf(cc), EPS);
            float no = fmaxf(sqrtf(doo), EPS);
            wsum += dco / (nc * no);
        }
    }

    __shared__ float s_part[4];
    if (lane == 0) s_part[wave] = wsum;
    __syncthreads();
    if (tid == 0)
        partial[blk] = s_part[0] + s_part[1] + s_part[2] + s_part[3];
}

__global__ __launch_bounds__(256) void rf_finalize_kernel(
    const float* __restrict__ partial, float* __restrict__ out, int nblk)
{
    const int tid = threadIdx.x;
    float s = 0.f;
    for (int i = tid; i < nblk; i += 256) s += partial[i];
    s = wave_reduce_sum(s);
    __shared__ float sm[4];
    if ((tid & 63) == 0) sm[tid >> 6] = s;
    __syncthreads();
    if (tid == 0) {
        float total = sm[0] + sm[1] + sm[2] + sm[3];
        out[0] = 1.f - total / (float)(nblk * 16);
    }
}

extern "C" void kernel_launch(void* const* d_in, const int* in_sizes, int n_in,
                              void* d_out, int out_size, void* d_ws, size_t ws_size,
                              hipStream_t stream) {
    const float* comp = (const float*)d_in[0];
    const float* orig = (const float*)d_in[1];
    float* out        = (float*)d_out;
    float* partial    = (float*)d_ws;   // nblk floats (18 KiB) of scratch

    const int B    = in_sizes[0] / (NTOK * D);
    const int nblk = B * NTOK;

    rf_partial_kernel<<<nblk, 256, 0, stream>>>(comp, orig, partial);
    rf_finalize_kernel<<<1, 256, 0, stream>>>(partial, out, nblk);
}

// Round 2
// 416.660 us; speedup vs baseline: 1.0008x; 1.0008x over previous
//
#include <hip/hip_runtime.h>

constexpr int D = 1024;
constexpr int CW = 24, OW = 96;
constexpr int NTOK = 576;          // 24*24
constexpr float EPS = 1e-12f;

__device__ inline float4 ld4(const float* p) { return *(const float4*)p; }

// One block (4 waves) per compressed token. Wave w owns window row w
// (4 consecutive original tokens = 16 KB contiguous). All global loads are
// issued before any use: c (1 float4/thread) first, then 16 o float4s per
// lane -> 17 outstanding VMEM ops per wave, fully coalesced (16 B/lane).
__global__ __launch_bounds__(256, 4) void rf_partial_kernel(
    const float* __restrict__ comp, const float* __restrict__ orig,
    float* __restrict__ partial)
{
    const int blk  = blockIdx.x;          // b*576 + t
    const int b    = blk / NTOK;
    const int t    = blk - b * NTOK;
    const int ch   = t / CW;
    const int cw   = t - ch * CW;
    const int tid  = threadIdx.x;
    const int wave = tid >> 6;
    const int lane = tid & 63;

    __shared__ float4 sc[256];            // the 4 KB compressed token

    // 1) c load, issued first so the LDS store only waits vmcnt(16)
    float4 cin = ld4(comp + (size_t)blk * D + tid * 4);

    // 2) all 16 o loads (wave handles row ch*4+wave, cols cw*4 .. cw*4+3)
    const float* orow = orig +
        ((size_t)b * (OW * OW) + (size_t)(ch * 4 + wave) * OW + cw * 4) * D;
    float4 o[4][4];
#pragma unroll
    for (int k = 0; k < 4; ++k)
#pragma unroll
        for (int j = 0; j < 4; ++j)
            o[k][j] = ld4(orow + k * D + j * 256 + lane * 4);

    // 3) stage c through LDS (each wave reads identical fragments back)
    sc[tid] = cin;
    __syncthreads();
    float4 c[4];
#pragma unroll
    for (int j = 0; j < 4; ++j) c[j] = sc[j * 64 + lane];

    // 4) per-lane partial sums: cc once, (dco,doo) per window token
    float cc = 0.f;
#pragma unroll
    for (int j = 0; j < 4; ++j)
        cc += c[j].x * c[j].x + c[j].y * c[j].y + c[j].z * c[j].z + c[j].w * c[j].w;

    float dco[4], doo[4];
#pragma unroll
    for (int k = 0; k < 4; ++k) {
        float a = 0.f, s = 0.f;
#pragma unroll
        for (int j = 0; j < 4; ++j) {
            const float4 ov = o[k][j];
            a += c[j].x * ov.x + c[j].y * ov.y + c[j].z * ov.z + c[j].w * ov.w;
            s += ov.x * ov.x + ov.y * ov.y + ov.z * ov.z + ov.w * ov.w;
        }
        dco[k] = a; doo[k] = s;
    }

    // 5) nine interleaved XOR butterflies (independent chains -> ILP)
#pragma unroll
    for (int off = 32; off > 0; off >>= 1) {
        cc += __shfl_xor(cc, off, 64);
#pragma unroll
        for (int k = 0; k < 4; ++k) {
            dco[k] += __shfl_xor(dco[k], off, 64);
            doo[k] += __shfl_xor(doo[k], off, 64);
        }
    }

    // 6) epilogue: per-wave sim sum, then block sum
    __shared__ float sp[4];
    if (lane == 0) {
        const float nc = fmaxf(sqrtf(cc), EPS);
        float wsum = 0.f;
#pragma unroll
        for (int k = 0; k < 4; ++k)
            wsum += dco[k] / (nc * fmaxf(sqrtf(doo[k]), EPS));
        sp[wave] = wsum;
    }
    __syncthreads();
    if (tid == 0)
        partial[blk] = sp[0] + sp[1] + sp[2] + sp[3];
}

__global__ __launch_bounds__(256) void rf_finalize_kernel(
    const float* __restrict__ partial, float* __restrict__ out, int nblk)
{
    const int tid = threadIdx.x;
    float s = 0.f;
    for (int i = tid; i < nblk; i += 256) s += partial[i];
#pragma unroll
    for (int off = 32; off > 0; off >>= 1) s += __shfl_xor(s, off, 64);
    __shared__ float sm[4];
    if ((tid & 63) == 0) sm[tid >> 6] = s;
    __syncthreads();
    if (tid == 0) {
        float total = sm[0] + sm[1] + sm[2] + sm[3];
        out[0] = 1.f - total / (float)(nblk * 16);
    }
}

extern "C" void kernel_launch(void* const* d_in, const int* in_sizes, int n_in,
                              void* d_out, int out_size, void* d_ws, size_t ws_size,
                              hipStream_t stream) {
    const float* comp = (const float*)d_in[0];
    const float* orig = (const float*)d_in[1];
    float* out        = (float*)d_out;
    float* partial    = (float*)d_ws;     // nblk floats (18 KiB) of scratch

    const int B    = in_sizes[0] / (NTOK * D);
    const int nblk = B * NTOK;

    rf_partial_kernel<<<nblk, 256, 0, stream>>>(comp, orig, partial);
    rf_finalize_kernel<<<1, 256, 0, stream>>>(partial, out, nblk);
}